// Round 8
// baseline (250.097 us; speedup 1.0000x reference)
//
#include <hip/hip_runtime.h>
#include <hip/hip_bf16.h>

// CrossNATBlock2D: B=1, H=W=128, C=128, HEADS=4, HD=32, K=7  (fp32 I/O)
// R8: k_fused = LN1 + K/V/Q projection (redundant over 10x10 union) + NATTEN
// attention, all in LDS per 4x4 pixel tile. No q/k/v global intermediates.
// ws: ao (4 MB bf16) + bf16 weights (~400 KB).

#define N_PIX 16384
#define C 128
#define HEADS 4
#define HD 32
#define HW 128

typedef __hip_bfloat16 bf16;
typedef __attribute__((ext_vector_type(8))) short bf16x8;
typedef __attribute__((ext_vector_type(4))) float f32x4;

__device__ __forceinline__ float b2f(bf16 v) { return __bfloat162float(v); }
__device__ __forceinline__ short f2bs(float f) {
    bf16 h = __float2bfloat16(f);
    return (short)__bfloat16_as_ushort(h);
}
__device__ __forceinline__ float bs2f(short s) {
    __hip_bfloat16_raw r; r.x = (unsigned short)s;
    return __bfloat162float(__hip_bfloat16(r));
}
__device__ __forceinline__ float wave_sum(float v) {
    for (int m = 1; m < 64; m <<= 1) v += __shfl_xor(v, m, 64);
    return v;
}

// ---------- kernel 0: convert weights fp32 -> bf16 into ws ----------
__global__ __launch_bounds__(256) void k_wconv(
    const float* __restrict__ qv_w, const float* __restrict__ k_w,
    const float* __restrict__ proj_w, const float* __restrict__ fc1_w,
    const float* __restrict__ fc2_w,
    short* __restrict__ wqv, short* __restrict__ wk, short* __restrict__ wproj,
    short* __restrict__ wfc1, short* __restrict__ wfc2) {
    const int i = blockIdx.x * 256 + threadIdx.x;
    if (i < 32768) wqv[i] = f2bs(qv_w[i]);
    if (i < 16384) { wk[i] = f2bs(k_w[i]); wproj[i] = f2bs(proj_w[i]); }
    if (i < 65536) { wfc1[i] = f2bs(fc1_w[i]); wfc2[i] = f2bs(fc2_w[i]); }
}

// ---------- kernel 1: fused LN1 + K/V/Q proj + NATTEN attention ----------
// one block per 4x4 pixel tile; union window 10x10 = 100 pixels (pad to 112).
__global__ __launch_bounds__(256) void k_fused(
    const float* __restrict__ x, const float* __restrict__ y,
    const short* __restrict__ wqv, const float* __restrict__ qv_b,
    const short* __restrict__ wk, const float* __restrict__ k_b,
    const float* __restrict__ n1_w, const float* __restrict__ n1_b,
    const float* __restrict__ rpb, bf16* __restrict__ ao) {
    __shared__ short U[112 * 136];    // y -> xn -> V
    __shared__ short KP[112 * 136];   // K -> P
    __shared__ short Qb[16 * 136];
    __shared__ float redS[100][2], redQ[100][2];
    __shared__ float muA[100], riA[100];
    const int t = threadIdx.x;
    const int wave = t >> 6, lane = t & 63, quad = lane >> 4, l15 = lane & 15;
    const int h = wave;
    const int i0 = (blockIdx.x >> 5) * 4;
    const int j0 = (blockIdx.x & 31) * 4;
    const int rs = min(max(i0 - 3, 0), 118);
    const int cs = min(max(j0 - 3, 0), 118);
    // ---- stage y -> U (bf16), zero pad rows of U and KP ----
    for (int u = t; u < 112 * 16; u += 256) {
        const int r = u >> 4, seg = u & 15;
        if (r < 100) {
            const int gi = rs + r / 10, gj = cs + r % 10;
            const float* yp = y + (size_t)(gi * HW + gj) * C + seg * 8;
            bf16x8 tmp;
#pragma unroll
            for (int jj = 0; jj < 8; jj++) tmp[jj] = f2bs(yp[jj]);
            *(bf16x8*)&U[r * 136 + seg * 8] = tmp;
        } else {
            bf16x8 z = {0, 0, 0, 0, 0, 0, 0, 0};
            *(bf16x8*)&U[r * 136 + seg * 8] = z;
            *(bf16x8*)&KP[r * 136 + seg * 8] = z;
        }
    }
    // ---- LN pass 1: row sums of x over union (coalesced, 2 rows/iter) ----
    for (int base = 0; base < 100; base += 2) {
        const int r = base + (wave >> 1);
        const int cc = (wave & 1) * 64 + lane;
        const int gi = rs + r / 10, gj = cs + r % 10;
        const float v = x[(size_t)(gi * HW + gj) * C + cc];
        const float s = wave_sum(v);
        const float q = wave_sum(v * v);
        if (lane == 0) { redS[r][wave & 1] = s; redQ[r][wave & 1] = q; }
    }
    __syncthreads();
    if (t < 100) {
        const float sm = redS[t][0] + redS[t][1];
        const float sq = redQ[t][0] + redQ[t][1];
        const float mu = sm * (1.f / 128.f);
        const float var = sq * (1.f / 128.f) - mu * mu;
        muA[t] = mu; riA[t] = rsqrtf(var + 1e-5f);
    }
    // ---- K = U @ wk^T + k_b -> KP ----
    for (int jt = wave; jt < 56; jt += 4) {
        const int mt = jt >> 3, nt = jt & 7;
        const int n = nt * 16 + l15;
        f32x4 acc = {0.f, 0.f, 0.f, 0.f};
        for (int kt = 0; kt < 4; kt++) {
            bf16x8 a = *(const bf16x8*)&U[(mt * 16 + l15) * 136 + kt * 32 + quad * 8];
            bf16x8 b = *(const bf16x8*)&wk[n * C + kt * 32 + quad * 8];
            acc = __builtin_amdgcn_mfma_f32_16x16x32_bf16(a, b, acc, 0, 0, 0);
        }
        const float bias = k_b[n];
        for (int r = 0; r < 4; r++) {
            const int row = mt * 16 + quad * 4 + r;
            if (row < 100) KP[row * 136 + n] = f2bs(acc[r] + bias);
        }
    }
    __syncthreads();
    // ---- xn = LN(x) over union -> U (2nd read of x) ----
    for (int e = t; e < 100 * 128; e += 256) {
        const int r = e >> 7, c = e & 127;
        const int gi = rs + r / 10, gj = cs + r % 10;
        const float v = x[(size_t)(gi * HW + gj) * C + c];
        U[r * 136 + c] = f2bs((v - muA[r]) * riA[r] * n1_w[c] + n1_b[c]);
    }
    __syncthreads();
    // ---- Q (own 16 pixels, scaled) -> Qb ; V (union) -> regs ----
    const float scale = 0.1767766952966369f;  // 1/sqrt(32)
    const int urow_own = (i0 + (l15 >> 2) - rs) * 10 + (j0 + (l15 & 3) - cs);
#pragma unroll
    for (int qi = 0; qi < 2; qi++) {
        const int nt = wave * 2 + qi, n = nt * 16 + l15;
        f32x4 acc = {0.f, 0.f, 0.f, 0.f};
        for (int kt = 0; kt < 4; kt++) {
            bf16x8 a = *(const bf16x8*)&U[urow_own * 136 + kt * 32 + quad * 8];
            bf16x8 b = *(const bf16x8*)&wqv[n * C + kt * 32 + quad * 8];
            acc = __builtin_amdgcn_mfma_f32_16x16x32_bf16(a, b, acc, 0, 0, 0);
        }
        const float bias = qv_b[n];
        for (int r = 0; r < 4; r++)
            Qb[(quad * 4 + r) * 136 + n] = f2bs((acc[r] + bias) * scale);
    }
    f32x4 Vacc[14];
#pragma unroll
    for (int j2 = 0; j2 < 14; j2++) {
        const int jt = j2 * 4 + wave;
        const int mt = jt >> 3, nt = jt & 7;
        const int n = nt * 16 + l15;
        f32x4 acc = {0.f, 0.f, 0.f, 0.f};
        for (int kt = 0; kt < 4; kt++) {
            bf16x8 a = *(const bf16x8*)&U[(mt * 16 + l15) * 136 + kt * 32 + quad * 8];
            bf16x8 b = *(const bf16x8*)&wqv[(size_t)(128 + n) * C + kt * 32 + quad * 8];
            acc = __builtin_amdgcn_mfma_f32_16x16x32_bf16(a, b, acc, 0, 0, 0);
        }
        Vacc[j2] = acc;
    }
    __syncthreads();
    // ---- write V over U ----
#pragma unroll
    for (int j2 = 0; j2 < 14; j2++) {
        const int jt = j2 * 4 + wave;
        const int mt = jt >> 3, nt = jt & 7;
        const int n = nt * 16 + l15;
        const float bias = qv_b[128 + n];
        for (int r = 0; r < 4; r++) {
            const int row = mt * 16 + quad * 4 + r;
            if (row < 100) U[row * 136 + n] = f2bs(Vacc[j2][r] + bias);
        }
    }
    __syncthreads();
    // ---- QK^T + masked bias + softmax ----
    const bf16x8 aQ = *(const bf16x8*)&Qb[l15 * 136 + h * HD + quad * 8];
    f32x4 S[7];
    int aiL[7], ajL[7]; bool inb[7];
    for (int nt = 0; nt < 7; nt++) {
        const int nb = nt * 16 + l15;
        aiL[nt] = rs + nb / 10;
        ajL[nt] = cs + nb % 10;
        inb[nt] = nb < 100;
        const bf16x8 bK = *(const bf16x8*)&KP[(nt * 16 + l15) * 136 + h * HD + quad * 8];
        f32x4 z = {0.f, 0.f, 0.f, 0.f};
        S[nt] = __builtin_amdgcn_mfma_f32_16x16x32_bf16(aQ, bK, z, 0, 0, 0);
    }
    const float* rpbh = rpb + h * 169;
    float sm[4];
    for (int r = 0; r < 4; r++) {
        const int m = quad * 4 + r;
        const int i = i0 + (m >> 2), j = j0 + (m & 3);
        const int shi = min(max(i - 3, 0), 121);
        const int swj = min(max(j - 3, 0), 121);
        float best = -1e30f;
        for (int nt = 0; nt < 7; nt++) {
            const int ai = aiL[nt], aj = ajL[nt];
            const bool valid = inb[nt] & (ai >= shi) & (ai <= shi + 6) & (aj >= swj) & (aj <= swj + 6);
            const int ri = min(max(ai - i + 6, 0), 12);
            const int rj = min(max(aj - j + 6, 0), 12);
            const float v = valid ? (S[nt][r] + rpbh[ri * 13 + rj]) : -1e30f;
            S[nt][r] = v;
            best = fmaxf(best, v);
        }
        for (int msk = 1; msk < 16; msk <<= 1) best = fmaxf(best, __shfl_xor(best, msk, 64));
        float s = 0.f;
        for (int nt = 0; nt < 7; nt++) {
            const float e = __expf(S[nt][r] - best);
            S[nt][r] = e;
            s += e;
        }
        for (int msk = 1; msk < 16; msk <<= 1) s += __shfl_xor(s, msk, 64);
        sm[r] = 1.f / s;
    }
    __syncthreads();   // all KP (K) reads done
    // ---- P -> KP (rows h*16.., zero cols 112..127) ----
    for (int r = 0; r < 4; r++) {
        short* prow = &KP[(h * 16 + quad * 4 + r) * 136];
        for (int nt = 0; nt < 7; nt++)
            prow[nt * 16 + l15] = f2bs(S[nt][r] * sm[r]);
        prow[112 + l15] = 0;
    }
    __syncthreads();
    // ---- PV -> ao ----
    f32x4 O0 = {0.f, 0.f, 0.f, 0.f}, O1 = {0.f, 0.f, 0.f, 0.f};
    for (int kt = 0; kt < 4; kt++) {
        const bf16x8 aP = *(const bf16x8*)&KP[(h * 16 + l15) * 136 + kt * 32 + quad * 8];
        for (int nt2 = 0; nt2 < 2; nt2++) {
            bf16x8 bV;
            const int ch = h * HD + nt2 * 16 + l15;
#pragma unroll
            for (int jj = 0; jj < 8; jj++) {
                const int nbr = kt * 32 + quad * 8 + jj;
                bV[jj] = (nbr < 100) ? U[nbr * 136 + ch] : (short)0;
            }
            if (nt2 == 0) O0 = __builtin_amdgcn_mfma_f32_16x16x32_bf16(aP, bV, O0, 0, 0, 0);
            else          O1 = __builtin_amdgcn_mfma_f32_16x16x32_bf16(aP, bV, O1, 0, 0, 0);
        }
    }
    for (int r = 0; r < 4; r++) {
        const int m = quad * 4 + r;
        const int p = (i0 + (m >> 2)) * HW + j0 + (m & 3);
        ao[(size_t)p * C + h * HD + l15] = __float2bfloat16(O0[r]);
        ao[(size_t)p * C + h * HD + 16 + l15] = __float2bfloat16(O1[r]);
    }
}

// ---------- kernel 2: proj + residual + LN2 + FC1 + GELU + FC2 + residual ----------
__global__ __launch_bounds__(512, 6) void k_mlp2(
    const float* __restrict__ x, const bf16* __restrict__ ao,
    const short* __restrict__ wproj, const float* __restrict__ proj_b,
    const float* __restrict__ n2_w, const float* __restrict__ n2_b,
    const short* __restrict__ wfc1, const float* __restrict__ fc1_b,
    const short* __restrict__ wfc2, const float* __restrict__ fc2_b,
    float* __restrict__ out) {
    __shared__ short x1b[32][136];
    __shared__ short xn[32][136];
    __shared__ short hb[32][520];
    __shared__ float redS[32][8], redQ[32][8];
    __shared__ float muA[32], riA[32];
    const int t = threadIdx.x;
    const int pix0 = blockIdx.x * 32;
    const int wave = t >> 6, lane = t & 63, quad = lane >> 4, l15 = lane & 15;
    for (int jt = wave; jt < 16; jt += 8) {
        const int mt = jt >> 3, nt = jt & 7;
        const int n = nt * 16 + l15;
        const bf16* aop = ao + (size_t)(pix0 + mt * 16 + l15) * C;
        f32x4 acc = {0.f, 0.f, 0.f, 0.f};
        for (int kt = 0; kt < 4; kt++) {
            bf16x8 a = *(const bf16x8*)(aop + kt * 32 + quad * 8);
            bf16x8 b = *(const bf16x8*)&wproj[n * C + kt * 32 + quad * 8];
            acc = __builtin_amdgcn_mfma_f32_16x16x32_bf16(a, b, acc, 0, 0, 0);
        }
        const float bias = proj_b[n];
        for (int r = 0; r < 4; r++) {
            const int m = mt * 16 + quad * 4 + r;
            x1b[m][n] = f2bs(x[(pix0 + m) * C + n] + acc[r] + bias);
        }
    }
    __syncthreads();
    if (t < 256) {
        const int r = t >> 3, s = t & 7;
        float sm = 0.f, sq = 0.f;
        for (int i = 0; i < 16; i++) { float v = bs2f(x1b[r][s * 16 + i]); sm += v; sq += v * v; }
        redS[r][s] = sm; redQ[r][s] = sq;
    }
    __syncthreads();
    if (t < 32) {
        float sm = 0.f, sq = 0.f;
        for (int s = 0; s < 8; s++) { sm += redS[t][s]; sq += redQ[t][s]; }
        const float mu = sm * (1.f / 128.f);
        const float var = sq * (1.f / 128.f) - mu * mu;
        muA[t] = mu; riA[t] = rsqrtf(var + 1e-5f);
    }
    __syncthreads();
    for (int e = t; e < 32 * 128; e += 512) {
        const int r = e >> 7, c = e & 127;
        xn[r][c] = f2bs((bs2f(x1b[r][c]) - muA[r]) * riA[r] * n2_w[c] + n2_b[c]);
    }
    __syncthreads();
    for (int jt = wave; jt < 64; jt += 8) {
        const int mt = jt >> 5, nt = jt & 31;
        const int n = nt * 16 + l15;
        f32x4 acc = {0.f, 0.f, 0.f, 0.f};
        for (int kt = 0; kt < 4; kt++) {
            bf16x8 a = *(const bf16x8*)&xn[mt * 16 + l15][kt * 32 + quad * 8];
            bf16x8 b = *(const bf16x8*)&wfc1[n * C + kt * 32 + quad * 8];
            acc = __builtin_amdgcn_mfma_f32_16x16x32_bf16(a, b, acc, 0, 0, 0);
        }
        const float bias = fc1_b[n];
        for (int r = 0; r < 4; r++) {
            const int m = mt * 16 + quad * 4 + r;
            float v = acc[r] + bias;
            v = 0.5f * v * (1.f + erff(v * 0.70710678118654752f));
            hb[m][n] = f2bs(v);
        }
    }
    __syncthreads();
    for (int jt = wave; jt < 16; jt += 8) {
        const int mt = jt >> 3, nt = jt & 7;
        const int n = nt * 16 + l15;
        f32x4 acc = {0.f, 0.f, 0.f, 0.f};
        for (int kt = 0; kt < 16; kt++) {
            bf16x8 a = *(const bf16x8*)&hb[mt * 16 + l15][kt * 32 + quad * 8];
            bf16x8 b = *(const bf16x8*)&wfc2[n * 512 + kt * 32 + quad * 8];
            acc = __builtin_amdgcn_mfma_f32_16x16x32_bf16(a, b, acc, 0, 0, 0);
        }
        const float bias = fc2_b[n];
        for (int r = 0; r < 4; r++) {
            const int m = mt * 16 + quad * 4 + r;
            out[(pix0 + m) * C + n] = acc[r] + bias + bs2f(x1b[m][n]);
        }
    }
}

extern "C" void kernel_launch(void* const* d_in, const int* in_sizes, int n_in,
                              void* d_out, int out_size, void* d_ws, size_t ws_size,
                              hipStream_t stream) {
    const float* x      = (const float*)d_in[0];
    const float* y      = (const float*)d_in[1];
    const float* qv_w   = (const float*)d_in[2];
    const float* qv_b   = (const float*)d_in[3];
    const float* k_w    = (const float*)d_in[4];
    const float* k_b    = (const float*)d_in[5];
    const float* rpb    = (const float*)d_in[6];
    const float* proj_w = (const float*)d_in[7];
    const float* proj_b = (const float*)d_in[8];
    const float* n1_w   = (const float*)d_in[9];
    const float* n1_b   = (const float*)d_in[10];
    const float* n2_w   = (const float*)d_in[11];
    const float* n2_b   = (const float*)d_in[12];
    const float* fc1_w  = (const float*)d_in[13];
    const float* fc1_b  = (const float*)d_in[14];
    const float* fc2_w  = (const float*)d_in[15];
    const float* fc2_b  = (const float*)d_in[16];
    float* out = (float*)d_out;

    bf16* ao = (bf16*)d_ws;                         // 16384*128 bf16 = 4 MB
    short* wqv  = (short*)(ao + (size_t)N_PIX * C); // 32768
    short* wk   = wqv + 32768;                      // 16384
    short* wproj= wk + 16384;                       // 16384
    short* wfc1 = wproj + 16384;                    // 65536
    short* wfc2 = wfc1 + 65536;                     // 65536  (total ~4.4 MB)

    k_wconv<<<256, 256, 0, stream>>>(qv_w, k_w, proj_w, fc1_w, fc2_w,
                                     wqv, wk, wproj, wfc1, wfc2);
    k_fused<<<1024, 256, 0, stream>>>(x, y, wqv, qv_b, wk, k_b, n1_w, n1_b, rpb, ao);
    k_mlp2<<<N_PIX / 32, 512, 0, stream>>>(x, ao, wproj, proj_b, n2_w, n2_b,
                                           wfc1, fc1_b, wfc2, fc2_b, out);
}

// Round 9
// 178.539 us; speedup vs baseline: 1.4008x; 1.4008x over previous
//
#include <hip/hip_runtime.h>
#include <hip/hip_bf16.h>

// CrossNATBlock2D: B=1, H=W=128, C=128, HEADS=4, HD=32, K=7  (fp32 I/O)
// R9: R7 structure, but k_attn = one wave per (4x4 tile, head): 64-thr blocks,
// 20.5 KB LDS (head's 32 channels only) -> 7 blocks/CU, no barriers.
// ws = qb/vb/kb (12 MB) + bf16 weights; ao aliases qb (disjoint ch per block).

#define N_PIX 16384
#define C 128
#define HEADS 4
#define HD 32
#define HW 128

typedef __hip_bfloat16 bf16;
typedef __attribute__((ext_vector_type(8))) short bf16x8;
typedef __attribute__((ext_vector_type(4))) float f32x4;

__device__ __forceinline__ float b2f(bf16 v) { return __bfloat162float(v); }
__device__ __forceinline__ short f2bs(float f) {
    bf16 h = __float2bfloat16(f);
    return (short)__bfloat16_as_ushort(h);
}
__device__ __forceinline__ float bs2f(short s) {
    __hip_bfloat16_raw r; r.x = (unsigned short)s;
    return __bfloat162float(__hip_bfloat16(r));
}

// ---------- kernel 0: convert weights fp32 -> bf16 into ws ----------
__global__ __launch_bounds__(256) void k_wconv(
    const float* __restrict__ qv_w, const float* __restrict__ k_w,
    const float* __restrict__ proj_w, const float* __restrict__ fc1_w,
    const float* __restrict__ fc2_w,
    short* __restrict__ wqv, short* __restrict__ wk, short* __restrict__ wproj,
    short* __restrict__ wfc1, short* __restrict__ wfc2) {
    const int i = blockIdx.x * 256 + threadIdx.x;
    if (i < 32768) wqv[i] = f2bs(qv_w[i]);
    if (i < 16384) { wk[i] = f2bs(k_w[i]); wproj[i] = f2bs(proj_w[i]); }
    if (i < 65536) { wfc1[i] = f2bs(fc1_w[i]); wfc2[i] = f2bs(fc2_w[i]); }
}

// ---------- kernel 1: LN1 + QV GEMM + K proj, MFMA, 32 pixels/block, 512 thr ----------
__global__ __launch_bounds__(512, 6) void k_qkv(
    const float* __restrict__ x, const float* __restrict__ y,
    const short* __restrict__ wqv, const float* __restrict__ qv_b,
    const short* __restrict__ wk, const float* __restrict__ k_b,
    const float* __restrict__ n1_w, const float* __restrict__ n1_b,
    bf16* __restrict__ qb, bf16* __restrict__ vb, bf16* __restrict__ kb) {
    __shared__ float xr[32][132];
    __shared__ short xn[32][136];
    __shared__ short yb[32][136];
    __shared__ float redS[32][8], redQ[32][8];
    __shared__ float muA[32], riA[32];
    const int t = threadIdx.x;
    const int pix0 = blockIdx.x * 32;
    for (int e = t; e < 32 * 128; e += 512) {
        const int r = e >> 7, c = e & 127;
        xr[r][c] = x[(pix0 + r) * C + c];
        yb[r][c] = f2bs(y[(pix0 + r) * C + c]);
    }
    __syncthreads();
    if (t < 256) {
        const int r = t >> 3, s = t & 7;
        float sm = 0.f, sq = 0.f;
        for (int i = 0; i < 16; i++) { float v = xr[r][s * 16 + i]; sm += v; sq += v * v; }
        redS[r][s] = sm; redQ[r][s] = sq;
    }
    __syncthreads();
    if (t < 32) {
        float sm = 0.f, sq = 0.f;
        for (int s = 0; s < 8; s++) { sm += redS[t][s]; sq += redQ[t][s]; }
        const float mu = sm * (1.f / 128.f);
        const float var = sq * (1.f / 128.f) - mu * mu;
        muA[t] = mu; riA[t] = rsqrtf(var + 1e-5f);
    }
    __syncthreads();
    for (int e = t; e < 32 * 128; e += 512) {
        const int r = e >> 7, c = e & 127;
        xn[r][c] = f2bs((xr[r][c] - muA[r]) * riA[r] * n1_w[c] + n1_b[c]);
    }
    __syncthreads();
    const int wave = t >> 6, lane = t & 63, quad = lane >> 4, l15 = lane & 15;
    const float scale = 0.1767766952966369f;  // 1/sqrt(32)
    for (int jt = wave; jt < 48; jt += 8) {
        const int mt = jt & 1, nt = jt >> 1;
        f32x4 acc = {0.f, 0.f, 0.f, 0.f};
        if (nt < 16) {  // qv GEMM
            const int n = nt * 16 + l15;
            for (int kt = 0; kt < 4; kt++) {
                bf16x8 a = *(const bf16x8*)&xn[mt * 16 + l15][kt * 32 + quad * 8];
                bf16x8 b = *(const bf16x8*)&wqv[n * C + kt * 32 + quad * 8];
                acc = __builtin_amdgcn_mfma_f32_16x16x32_bf16(a, b, acc, 0, 0, 0);
            }
            const float bias = qv_b[n];
            for (int r = 0; r < 4; r++) {
                const int m = mt * 16 + quad * 4 + r;
                const float v = acc[r] + bias;
                if (n < C) qb[(pix0 + m) * C + n] = __float2bfloat16(v * scale);
                else       vb[(pix0 + m) * C + (n - C)] = __float2bfloat16(v);
            }
        } else {       // k GEMM
            const int n = (nt - 16) * 16 + l15;
            for (int kt = 0; kt < 4; kt++) {
                bf16x8 a = *(const bf16x8*)&yb[mt * 16 + l15][kt * 32 + quad * 8];
                bf16x8 b = *(const bf16x8*)&wk[n * C + kt * 32 + quad * 8];
                acc = __builtin_amdgcn_mfma_f32_16x16x32_bf16(a, b, acc, 0, 0, 0);
            }
            const float bias = k_b[n];
            for (int r = 0; r < 4; r++) {
                const int m = mt * 16 + quad * 4 + r;
                kb[(pix0 + m) * C + n] = __float2bfloat16(acc[r] + bias);
            }
        }
    }
}

// ---------- kernel 2: NATTEN 7x7 MFMA attention, one wave per (4x4 tile, head) ----------
// 64-thr blocks; LDS = K/V union (100 rows x 32 head-channels) + P = 20.5 KB.
// No __syncthreads (single wave). ao aliases qb: each block reads q then writes
// ao at the SAME (pixel, channel) range; cross-block ranges are disjoint.
__global__ __launch_bounds__(64) void k_attn(
    const bf16* qb, const bf16* __restrict__ kb,
    const bf16* __restrict__ vb, const float* __restrict__ rpb,
    bf16* ao) {
    __shared__ short Kl[112 * 36];   // rows >=100 uninitialized (masked out)
    __shared__ short Vl[112 * 36];
    __shared__ short Pl[16 * 136];   // P, cols 112..127 zeroed
    const int t = threadIdx.x;       // lane 0..63
    const int quad = t >> 4, l15 = t & 15;
    const int tile = blockIdx.x >> 2, h = blockIdx.x & 3;
    const int i0 = (tile >> 5) * 4;
    const int j0 = (tile & 31) * 4;
    const int rs = min(max(i0 - 3, 0), 118);
    const int cs = min(max(j0 - 3, 0), 118);
    // ---- stage K and V union (100 rows x 32 ch = 4 segs of 16B), 800 uint4 ----
    for (int u = t; u < 800; u += 64) {
        const int tv = (u >= 400) ? 1 : 0;
        const int uu = tv ? u - 400 : u;
        const int r = uu >> 2, seg = uu & 3;
        const size_t g = (size_t)((rs + r / 10) * HW + cs + r % 10) * C + h * HD + seg * 8;
        const uint4 d = *(const uint4*)((tv ? vb : kb) + g);
        *(uint4*)&(tv ? Vl : Kl)[r * 36 + seg * 8] = d;
    }
    // ---- QK^T: S[16 px][112 nbrs] (HD=32 -> 1 MFMA per N-tile) ----
    const int pA = (i0 + (l15 >> 2)) * HW + j0 + (l15 & 3);
    const bf16x8 aQ = *(const bf16x8*)(qb + (size_t)pA * C + h * HD + quad * 8);
    f32x4 S[7];
    int aiL[7], ajL[7]; bool inb[7];
#pragma unroll
    for (int nt = 0; nt < 7; nt++) {
        const int nb = nt * 16 + l15;
        aiL[nt] = rs + nb / 10;
        ajL[nt] = cs + nb % 10;
        inb[nt] = nb < 100;
        const bf16x8 bK = *(const bf16x8*)&Kl[(nt * 16 + l15) * 36 + quad * 8];
        f32x4 z = {0.f, 0.f, 0.f, 0.f};
        S[nt] = __builtin_amdgcn_mfma_f32_16x16x32_bf16(aQ, bK, z, 0, 0, 0);
    }
    // ---- bias + validity mask + softmax (C-layout: row=quad*4+r, col=nt*16+l15) ----
    const float* rpbh = rpb + h * 169;
    float sm[4];
#pragma unroll
    for (int r = 0; r < 4; r++) {
        const int m = quad * 4 + r;
        const int i = i0 + (m >> 2), j = j0 + (m & 3);
        const int shi = min(max(i - 3, 0), 121);
        const int swj = min(max(j - 3, 0), 121);
        float best = -1e30f;
#pragma unroll
        for (int nt = 0; nt < 7; nt++) {
            const int ai = aiL[nt], aj = ajL[nt];
            const bool valid = inb[nt] & (ai >= shi) & (ai <= shi + 6) & (aj >= swj) & (aj <= swj + 6);
            const int ri = min(max(ai - i + 6, 0), 12);
            const int rj = min(max(aj - j + 6, 0), 12);
            const float v = valid ? (S[nt][r] + rpbh[ri * 13 + rj]) : -1e30f;
            S[nt][r] = v;
            best = fmaxf(best, v);
        }
        for (int msk = 1; msk < 16; msk <<= 1) best = fmaxf(best, __shfl_xor(best, msk, 64));
        float s = 0.f;
#pragma unroll
        for (int nt = 0; nt < 7; nt++) {
            const float e = __expf(S[nt][r] - best);
            S[nt][r] = e;
            s += e;
        }
        for (int msk = 1; msk < 16; msk <<= 1) s += __shfl_xor(s, msk, 64);
        sm[r] = 1.f / s;
    }
    // ---- write P (bf16) -> Pl, zero cols 112..127 ----
#pragma unroll
    for (int r = 0; r < 4; r++) {
        short* prow = &Pl[(quad * 4 + r) * 136];
#pragma unroll
        for (int nt = 0; nt < 7; nt++)
            prow[nt * 16 + l15] = f2bs(S[nt][r] * sm[r]);
        prow[112 + l15] = 0;
    }
    // ---- PV: out[16 px][32 ch] ----
    f32x4 O0 = {0.f, 0.f, 0.f, 0.f}, O1 = {0.f, 0.f, 0.f, 0.f};
#pragma unroll
    for (int kt = 0; kt < 4; kt++) {
        const bf16x8 aP = *(const bf16x8*)&Pl[l15 * 136 + kt * 32 + quad * 8];
#pragma unroll
        for (int nt2 = 0; nt2 < 2; nt2++) {
            bf16x8 bV;
            const int ch = nt2 * 16 + l15;
#pragma unroll
            for (int jj = 0; jj < 8; jj++) {
                const int nbr = kt * 32 + quad * 8 + jj;
                bV[jj] = (nbr < 100) ? Vl[nbr * 36 + ch] : (short)0;
            }
            if (nt2 == 0) O0 = __builtin_amdgcn_mfma_f32_16x16x32_bf16(aP, bV, O0, 0, 0, 0);
            else          O1 = __builtin_amdgcn_mfma_f32_16x16x32_bf16(aP, bV, O1, 0, 0, 0);
        }
    }
#pragma unroll
    for (int r = 0; r < 4; r++) {
        const int m = quad * 4 + r;
        const int p = (i0 + (m >> 2)) * HW + j0 + (m & 3);
        ao[(size_t)p * C + h * HD + l15] = __float2bfloat16(O0[r]);
        ao[(size_t)p * C + h * HD + 16 + l15] = __float2bfloat16(O1[r]);
    }
}

// ---------- kernel 3: proj + residual + LN2 + FC1 + GELU + FC2 + residual ----------
__global__ __launch_bounds__(512, 6) void k_mlp2(
    const float* __restrict__ x, const bf16* __restrict__ ao,
    const short* __restrict__ wproj, const float* __restrict__ proj_b,
    const float* __restrict__ n2_w, const float* __restrict__ n2_b,
    const short* __restrict__ wfc1, const float* __restrict__ fc1_b,
    const short* __restrict__ wfc2, const float* __restrict__ fc2_b,
    float* __restrict__ out) {
    __shared__ short x1b[32][136];
    __shared__ short xn[32][136];
    __shared__ short hb[32][520];
    __shared__ float redS[32][8], redQ[32][8];
    __shared__ float muA[32], riA[32];
    const int t = threadIdx.x;
    const int pix0 = blockIdx.x * 32;
    const int wave = t >> 6, lane = t & 63, quad = lane >> 4, l15 = lane & 15;
    for (int jt = wave; jt < 16; jt += 8) {
        const int mt = jt >> 3, nt = jt & 7;
        const int n = nt * 16 + l15;
        const bf16* aop = ao + (size_t)(pix0 + mt * 16 + l15) * C;
        f32x4 acc = {0.f, 0.f, 0.f, 0.f};
        for (int kt = 0; kt < 4; kt++) {
            bf16x8 a = *(const bf16x8*)(aop + kt * 32 + quad * 8);
            bf16x8 b = *(const bf16x8*)&wproj[n * C + kt * 32 + quad * 8];
            acc = __builtin_amdgcn_mfma_f32_16x16x32_bf16(a, b, acc, 0, 0, 0);
        }
        const float bias = proj_b[n];
        for (int r = 0; r < 4; r++) {
            const int m = mt * 16 + quad * 4 + r;
            x1b[m][n] = f2bs(x[(pix0 + m) * C + n] + acc[r] + bias);
        }
    }
    __syncthreads();
    if (t < 256) {
        const int r = t >> 3, s = t & 7;
        float sm = 0.f, sq = 0.f;
        for (int i = 0; i < 16; i++) { float v = bs2f(x1b[r][s * 16 + i]); sm += v; sq += v * v; }
        redS[r][s] = sm; redQ[r][s] = sq;
    }
    __syncthreads();
    if (t < 32) {
        float sm = 0.f, sq = 0.f;
        for (int s = 0; s < 8; s++) { sm += redS[t][s]; sq += redQ[t][s]; }
        const float mu = sm * (1.f / 128.f);
        const float var = sq * (1.f / 128.f) - mu * mu;
        muA[t] = mu; riA[t] = rsqrtf(var + 1e-5f);
    }
    __syncthreads();
    for (int e = t; e < 32 * 128; e += 512) {
        const int r = e >> 7, c = e & 127;
        xn[r][c] = f2bs((bs2f(x1b[r][c]) - muA[r]) * riA[r] * n2_w[c] + n2_b[c]);
    }
    __syncthreads();
    for (int jt = wave; jt < 64; jt += 8) {
        const int mt = jt >> 5, nt = jt & 31;
        const int n = nt * 16 + l15;
        f32x4 acc = {0.f, 0.f, 0.f, 0.f};
        for (int kt = 0; kt < 4; kt++) {
            bf16x8 a = *(const bf16x8*)&xn[mt * 16 + l15][kt * 32 + quad * 8];
            bf16x8 b = *(const bf16x8*)&wfc1[n * C + kt * 32 + quad * 8];
            acc = __builtin_amdgcn_mfma_f32_16x16x32_bf16(a, b, acc, 0, 0, 0);
        }
        const float bias = fc1_b[n];
        for (int r = 0; r < 4; r++) {
            const int m = mt * 16 + quad * 4 + r;
            float v = acc[r] + bias;
            v = 0.5f * v * (1.f + erff(v * 0.70710678118654752f));
            hb[m][n] = f2bs(v);
        }
    }
    __syncthreads();
    for (int jt = wave; jt < 16; jt += 8) {
        const int mt = jt >> 3, nt = jt & 7;
        const int n = nt * 16 + l15;
        f32x4 acc = {0.f, 0.f, 0.f, 0.f};
#pragma unroll
        for (int kt = 0; kt < 16; kt++) {
            bf16x8 a = *(const bf16x8*)&hb[mt * 16 + l15][kt * 32 + quad * 8];
            bf16x8 b = *(const bf16x8*)&wfc2[n * 512 + kt * 32 + quad * 8];
            acc = __builtin_amdgcn_mfma_f32_16x16x32_bf16(a, b, acc, 0, 0, 0);
        }
        const float bias = fc2_b[n];
        for (int r = 0; r < 4; r++) {
            const int m = mt * 16 + quad * 4 + r;
            out[(pix0 + m) * C + n] = acc[r] + bias + bs2f(x1b[m][n]);
        }
    }
}

extern "C" void kernel_launch(void* const* d_in, const int* in_sizes, int n_in,
                              void* d_out, int out_size, void* d_ws, size_t ws_size,
                              hipStream_t stream) {
    const float* x      = (const float*)d_in[0];
    const float* y      = (const float*)d_in[1];
    const float* qv_w   = (const float*)d_in[2];
    const float* qv_b   = (const float*)d_in[3];
    const float* k_w    = (const float*)d_in[4];
    const float* k_b    = (const float*)d_in[5];
    const float* rpb    = (const float*)d_in[6];
    const float* proj_w = (const float*)d_in[7];
    const float* proj_b = (const float*)d_in[8];
    const float* n1_w   = (const float*)d_in[9];
    const float* n1_b   = (const float*)d_in[10];
    const float* n2_w   = (const float*)d_in[11];
    const float* n2_b   = (const float*)d_in[12];
    const float* fc1_w  = (const float*)d_in[13];
    const float* fc1_b  = (const float*)d_in[14];
    const float* fc2_w  = (const float*)d_in[15];
    const float* fc2_b  = (const float*)d_in[16];
    float* out = (float*)d_out;

    bf16* qb  = (bf16*)d_ws;                        // later reused as ao (alias)
    bf16* vb  = qb + (size_t)N_PIX * C;
    bf16* kb  = vb + (size_t)N_PIX * C;
    short* wqv  = (short*)(kb + (size_t)N_PIX * C); // 32768
    short* wk   = wqv + 32768;                      // 16384
    short* wproj= wk + 16384;                       // 16384
    short* wfc1 = wproj + 16384;                    // 65536
    short* wfc2 = wfc1 + 65536;                     // 65536  (total ~12.4 MB)
    bf16* ao = qb;                                  // alias: safe (see k_attn)

    k_wconv<<<256, 256, 0, stream>>>(qv_w, k_w, proj_w, fc1_w, fc2_w,
                                     wqv, wk, wproj, wfc1, wfc2);
    k_qkv<<<N_PIX / 32, 512, 0, stream>>>(x, y, wqv, qv_b, wk, k_b, n1_w, n1_b, qb, vb, kb);
    k_attn<<<4096, 64, 0, stream>>>(qb, kb, vb, rpb, ao);
    k_mlp2<<<N_PIX / 32, 512, 0, stream>>>(x, ao, wproj, proj_b, n2_w, n2_b,
                                           wfc1, fc1_b, wfc2, fc2_b, out);
}

// Round 10
// 173.669 us; speedup vs baseline: 1.4401x; 1.0280x over previous
//
#include <hip/hip_runtime.h>
#include <hip/hip_bf16.h>

// CrossNATBlock2D: B=1, H=W=128, C=128, HEADS=4, HD=32, K=7  (fp32 I/O)
// R10: R7 structure (best e2e 176us). Chain cuts: LN finalize folded into the
// stats phase via intra-wave shfl (one barrier fewer in k_qkv/k_mlp2), GELU via
// tanh/__expf instead of erff. k_attn = R7's 256-thr 4x4-tile version.

#define N_PIX 16384
#define C 128
#define HEADS 4
#define HD 32
#define HW 128

typedef __hip_bfloat16 bf16;
typedef __attribute__((ext_vector_type(8))) short bf16x8;
typedef __attribute__((ext_vector_type(4))) float f32x4;

__device__ __forceinline__ float b2f(bf16 v) { return __bfloat162float(v); }
__device__ __forceinline__ short f2bs(float f) {
    bf16 h = __float2bfloat16(f);
    return (short)__bfloat16_as_ushort(h);
}
__device__ __forceinline__ float bs2f(short s) {
    __hip_bfloat16_raw r; r.x = (unsigned short)s;
    return __bfloat162float(__hip_bfloat16(r));
}
__device__ __forceinline__ float gelu_f(float v) {
    // tanh-form GELU: 0.5v(1+tanh(0.7978845608(v+0.044715 v^3)))
    const float z = 1.5957691216f * (v + 0.044715f * v * v * v);  // 2*0.79788456*(...)
    return v / (1.f + __expf(-z));  // 0.5v(1+tanh(z/2)) == v*sigmoid(z)
}

// ---------- kernel 0: convert weights fp32 -> bf16 into ws ----------
__global__ __launch_bounds__(256) void k_wconv(
    const float* __restrict__ qv_w, const float* __restrict__ k_w,
    const float* __restrict__ proj_w, const float* __restrict__ fc1_w,
    const float* __restrict__ fc2_w,
    short* __restrict__ wqv, short* __restrict__ wk, short* __restrict__ wproj,
    short* __restrict__ wfc1, short* __restrict__ wfc2) {
    const int i = blockIdx.x * 256 + threadIdx.x;
    if (i < 32768) wqv[i] = f2bs(qv_w[i]);
    if (i < 16384) { wk[i] = f2bs(k_w[i]); wproj[i] = f2bs(proj_w[i]); }
    if (i < 65536) { wfc1[i] = f2bs(fc1_w[i]); wfc2[i] = f2bs(fc2_w[i]); }
}

// ---------- kernel 1: LN1 + QV GEMM + K proj, MFMA, 32 pixels/block, 512 thr ----------
__global__ __launch_bounds__(512, 6) void k_qkv(
    const float* __restrict__ x, const float* __restrict__ y,
    const short* __restrict__ wqv, const float* __restrict__ qv_b,
    const short* __restrict__ wk, const float* __restrict__ k_b,
    const float* __restrict__ n1_w, const float* __restrict__ n1_b,
    bf16* __restrict__ qb, bf16* __restrict__ vb, bf16* __restrict__ kb) {
    __shared__ float xr[32][132];
    __shared__ short xn[32][136];
    __shared__ short yb[32][136];
    __shared__ float muA[32], riA[32];
    const int t = threadIdx.x;
    const int pix0 = blockIdx.x * 32;
    for (int e = t; e < 32 * 128; e += 512) {
        const int r = e >> 7, c = e & 127;
        xr[r][c] = x[(pix0 + r) * C + c];
        yb[r][c] = f2bs(y[(pix0 + r) * C + c]);
    }
    __syncthreads();
    if (t < 256) {
        const int r = t >> 3, s = t & 7;   // 8 lanes (same wave) per row
        float sm = 0.f, sq = 0.f;
        for (int i = 0; i < 16; i++) { float v = xr[r][s * 16 + i]; sm += v; sq += v * v; }
        for (int m = 1; m < 8; m <<= 1) { sm += __shfl_xor(sm, m, 64); sq += __shfl_xor(sq, m, 64); }
        if (s == 0) {
            const float mu = sm * (1.f / 128.f);
            const float var = sq * (1.f / 128.f) - mu * mu;
            muA[r] = mu; riA[r] = rsqrtf(var + 1e-5f);
        }
    }
    __syncthreads();
    for (int e = t; e < 32 * 128; e += 512) {
        const int r = e >> 7, c = e & 127;
        xn[r][c] = f2bs((xr[r][c] - muA[r]) * riA[r] * n1_w[c] + n1_b[c]);
    }
    __syncthreads();
    const int wave = t >> 6, lane = t & 63, quad = lane >> 4, l15 = lane & 15;
    const float scale = 0.1767766952966369f;  // 1/sqrt(32)
    for (int jt = wave; jt < 48; jt += 8) {
        const int mt = jt & 1, nt = jt >> 1;
        f32x4 acc = {0.f, 0.f, 0.f, 0.f};
        if (nt < 16) {  // qv GEMM
            const int n = nt * 16 + l15;
            for (int kt = 0; kt < 4; kt++) {
                bf16x8 a = *(const bf16x8*)&xn[mt * 16 + l15][kt * 32 + quad * 8];
                bf16x8 b = *(const bf16x8*)&wqv[n * C + kt * 32 + quad * 8];
                acc = __builtin_amdgcn_mfma_f32_16x16x32_bf16(a, b, acc, 0, 0, 0);
            }
            const float bias = qv_b[n];
            for (int r = 0; r < 4; r++) {
                const int m = mt * 16 + quad * 4 + r;
                const float v = acc[r] + bias;
                if (n < C) qb[(pix0 + m) * C + n] = __float2bfloat16(v * scale);
                else       vb[(pix0 + m) * C + (n - C)] = __float2bfloat16(v);
            }
        } else {       // k GEMM
            const int n = (nt - 16) * 16 + l15;
            for (int kt = 0; kt < 4; kt++) {
                bf16x8 a = *(const bf16x8*)&yb[mt * 16 + l15][kt * 32 + quad * 8];
                bf16x8 b = *(const bf16x8*)&wk[n * C + kt * 32 + quad * 8];
                acc = __builtin_amdgcn_mfma_f32_16x16x32_bf16(a, b, acc, 0, 0, 0);
            }
            const float bias = k_b[n];
            for (int r = 0; r < 4; r++) {
                const int m = mt * 16 + quad * 4 + r;
                kb[(pix0 + m) * C + n] = __float2bfloat16(acc[r] + bias);
            }
        }
    }
}

// ---------- kernel 2: NATTEN 7x7 MFMA attention, 4x4 pixel tile per block ----------
// union window = 10x10 = 100 neighbors. ao aliases qb (block reads only own q,
// barrier-ordered before writes; disjoint pixels across blocks).
__global__ __launch_bounds__(256) void k_attn(
    const bf16* qb, const bf16* __restrict__ kb,
    const bf16* __restrict__ vb, const float* __restrict__ rpb,
    bf16* ao) {
    __shared__ short KP[100 * 132];   // K during QK^T, then P[4][16] stride 136
    __shared__ short Vl[100 * 132];
    const int t = threadIdx.x;
    const int h = t >> 6, lane = t & 63, quad = lane >> 4, l15 = lane & 15;
    const int i0 = (blockIdx.x >> 5) * 4;      // 32 row-tiles
    const int j0 = (blockIdx.x & 31) * 4;      // 32 col-tiles
    const int rs = min(max(i0 - 3, 0), 118);   // union rows [rs, rs+9]
    const int cs = min(max(j0 - 3, 0), 118);   // union cols [cs, cs+9]
    // stage K and V union windows (100 rows x 128 ch, 16B chunks)
    for (int u = t; u < 100 * 16 * 2; u += 256) {
        const int tv = (u >= 1600) ? 1 : 0;
        const int uu = tv ? u - 1600 : u;
        const int r = uu >> 4, seg = uu & 15;
        const int wr = r / 10, wc = r % 10;
        const size_t g = (size_t)((rs + wr) * HW + cs + wc) * C + seg * 8;
        const uint4 d = *(const uint4*)((tv ? vb : kb) + g);
        *(uint4*)&(tv ? Vl : KP)[r * 132 + seg * 8] = d;
    }
    __syncthreads();
    // ---- QK^T: S[16 pixels][112 (100 valid)], per wave = head ----
    const int pA = (i0 + (l15 >> 2)) * HW + j0 + (l15 & 3);
    const bf16x8 aQ = *(const bf16x8*)(qb + (size_t)pA * C + h * HD + quad * 8);
    f32x4 S[7];
    int aiL[7], ajL[7]; bool inb[7];
    for (int nt = 0; nt < 7; nt++) {
        const int nb = nt * 16 + l15;
        aiL[nt] = rs + nb / 10;
        ajL[nt] = cs + nb % 10;
        inb[nt] = nb < 100;
        const bf16x8 bK = *(const bf16x8*)&KP[(nt * 16 + l15) * 132 + h * HD + quad * 8];
        f32x4 z = {0.f, 0.f, 0.f, 0.f};
        S[nt] = __builtin_amdgcn_mfma_f32_16x16x32_bf16(aQ, bK, z, 0, 0, 0);
    }
    // ---- bias + validity mask + softmax (C-layout: row=quad*4+r, col=nt*16+l15) ----
    const float* rpbh = rpb + h * 169;
    float sm[4];
    for (int r = 0; r < 4; r++) {
        const int m = quad * 4 + r;
        const int i = i0 + (m >> 2), j = j0 + (m & 3);
        const int shi = min(max(i - 3, 0), 121);
        const int swj = min(max(j - 3, 0), 121);
        float best = -1e30f;
        for (int nt = 0; nt < 7; nt++) {
            const int ai = aiL[nt], aj = ajL[nt];
            const bool valid = inb[nt] & (ai >= shi) & (ai <= shi + 6) & (aj >= swj) & (aj <= swj + 6);
            const int ri = min(max(ai - i + 6, 0), 12);
            const int rj = min(max(aj - j + 6, 0), 12);
            const float v = valid ? (S[nt][r] + rpbh[ri * 13 + rj]) : -1e30f;
            S[nt][r] = v;
            best = fmaxf(best, v);
        }
        for (int msk = 1; msk < 16; msk <<= 1) best = fmaxf(best, __shfl_xor(best, msk, 64));
        float s = 0.f;
        for (int nt = 0; nt < 7; nt++) {
            const float e = __expf(S[nt][r] - best);
            S[nt][r] = e;
            s += e;
        }
        for (int msk = 1; msk < 16; msk <<= 1) s += __shfl_xor(s, msk, 64);
        sm[r] = 1.f / s;
    }
    __syncthreads();   // all waves done reading KP as K
    // ---- write P (bf16) over KP: row stride 136, zero pad cols 112..127 ----
    for (int r = 0; r < 4; r++) {
        short* prow = &KP[(h * 16 + quad * 4 + r) * 136];
        for (int nt = 0; nt < 7; nt++)
            prow[nt * 16 + l15] = f2bs(S[nt][r] * sm[r]);
        prow[112 + l15] = 0;
    }
    __syncthreads();
    // ---- PV: out[16][32] per head ----
    f32x4 O0 = {0.f, 0.f, 0.f, 0.f}, O1 = {0.f, 0.f, 0.f, 0.f};
    for (int kt = 0; kt < 4; kt++) {
        const bf16x8 aP = *(const bf16x8*)&KP[(h * 16 + l15) * 136 + kt * 32 + quad * 8];
        for (int nt2 = 0; nt2 < 2; nt2++) {
            bf16x8 bV;
            const int ch = h * HD + nt2 * 16 + l15;
#pragma unroll
            for (int jj = 0; jj < 8; jj++) {
                const int nbr = kt * 32 + quad * 8 + jj;
                bV[jj] = (nbr < 100) ? Vl[nbr * 132 + ch] : (short)0;
            }
            if (nt2 == 0) O0 = __builtin_amdgcn_mfma_f32_16x16x32_bf16(aP, bV, O0, 0, 0, 0);
            else          O1 = __builtin_amdgcn_mfma_f32_16x16x32_bf16(aP, bV, O1, 0, 0, 0);
        }
    }
    for (int r = 0; r < 4; r++) {
        const int m = quad * 4 + r;
        const int p = (i0 + (m >> 2)) * HW + j0 + (m & 3);
        ao[(size_t)p * C + h * HD + l15] = __float2bfloat16(O0[r]);
        ao[(size_t)p * C + h * HD + 16 + l15] = __float2bfloat16(O1[r]);
    }
}

// ---------- kernel 3: proj + residual + LN2 + FC1 + GELU + FC2 + residual ----------
__global__ __launch_bounds__(512, 6) void k_mlp2(
    const float* __restrict__ x, const bf16* __restrict__ ao,
    const short* __restrict__ wproj, const float* __restrict__ proj_b,
    const float* __restrict__ n2_w, const float* __restrict__ n2_b,
    const short* __restrict__ wfc1, const float* __restrict__ fc1_b,
    const short* __restrict__ wfc2, const float* __restrict__ fc2_b,
    float* __restrict__ out) {
    __shared__ short x1b[32][136];
    __shared__ short xn[32][136];
    __shared__ short hb[32][520];
    __shared__ float muA[32], riA[32];
    const int t = threadIdx.x;
    const int pix0 = blockIdx.x * 32;
    const int wave = t >> 6, lane = t & 63, quad = lane >> 4, l15 = lane & 15;
    for (int jt = wave; jt < 16; jt += 8) {
        const int mt = jt >> 3, nt = jt & 7;
        const int n = nt * 16 + l15;
        const bf16* aop = ao + (size_t)(pix0 + mt * 16 + l15) * C;
        f32x4 acc = {0.f, 0.f, 0.f, 0.f};
        for (int kt = 0; kt < 4; kt++) {
            bf16x8 a = *(const bf16x8*)(aop + kt * 32 + quad * 8);
            bf16x8 b = *(const bf16x8*)&wproj[n * C + kt * 32 + quad * 8];
            acc = __builtin_amdgcn_mfma_f32_16x16x32_bf16(a, b, acc, 0, 0, 0);
        }
        const float bias = proj_b[n];
        for (int r = 0; r < 4; r++) {
            const int m = mt * 16 + quad * 4 + r;
            x1b[m][n] = f2bs(x[(pix0 + m) * C + n] + acc[r] + bias);
        }
    }
    __syncthreads();
    if (t < 256) {
        const int r = t >> 3, s = t & 7;   // 8 lanes (same wave) per row
        float sm = 0.f, sq = 0.f;
        for (int i = 0; i < 16; i++) { float v = bs2f(x1b[r][s * 16 + i]); sm += v; sq += v * v; }
        for (int m = 1; m < 8; m <<= 1) { sm += __shfl_xor(sm, m, 64); sq += __shfl_xor(sq, m, 64); }
        if (s == 0) {
            const float mu = sm * (1.f / 128.f);
            const float var = sq * (1.f / 128.f) - mu * mu;
            muA[r] = mu; riA[r] = rsqrtf(var + 1e-5f);
        }
    }
    __syncthreads();
    for (int e = t; e < 32 * 128; e += 512) {
        const int r = e >> 7, c = e & 127;
        xn[r][c] = f2bs((bs2f(x1b[r][c]) - muA[r]) * riA[r] * n2_w[c] + n2_b[c]);
    }
    __syncthreads();
    for (int jt = wave; jt < 64; jt += 8) {
        const int mt = jt >> 5, nt = jt & 31;
        const int n = nt * 16 + l15;
        f32x4 acc = {0.f, 0.f, 0.f, 0.f};
        for (int kt = 0; kt < 4; kt++) {
            bf16x8 a = *(const bf16x8*)&xn[mt * 16 + l15][kt * 32 + quad * 8];
            bf16x8 b = *(const bf16x8*)&wfc1[n * C + kt * 32 + quad * 8];
            acc = __builtin_amdgcn_mfma_f32_16x16x32_bf16(a, b, acc, 0, 0, 0);
        }
        const float bias = fc1_b[n];
        for (int r = 0; r < 4; r++) {
            const int m = mt * 16 + quad * 4 + r;
            hb[m][n] = f2bs(gelu_f(acc[r] + bias));
        }
    }
    __syncthreads();
    for (int jt = wave; jt < 16; jt += 8) {
        const int mt = jt >> 3, nt = jt & 7;
        const int n = nt * 16 + l15;
        f32x4 acc = {0.f, 0.f, 0.f, 0.f};
#pragma unroll
        for (int kt = 0; kt < 16; kt++) {
            bf16x8 a = *(const bf16x8*)&hb[mt * 16 + l15][kt * 32 + quad * 8];
            bf16x8 b = *(const bf16x8*)&wfc2[n * 512 + kt * 32 + quad * 8];
            acc = __builtin_amdgcn_mfma_f32_16x16x32_bf16(a, b, acc, 0, 0, 0);
        }
        const float bias = fc2_b[n];
        for (int r = 0; r < 4; r++) {
            const int m = mt * 16 + quad * 4 + r;
            out[(pix0 + m) * C + n] = acc[r] + bias + bs2f(x1b[m][n]);
        }
    }
}

extern "C" void kernel_launch(void* const* d_in, const int* in_sizes, int n_in,
                              void* d_out, int out_size, void* d_ws, size_t ws_size,
                              hipStream_t stream) {
    const float* x      = (const float*)d_in[0];
    const float* y      = (const float*)d_in[1];
    const float* qv_w   = (const float*)d_in[2];
    const float* qv_b   = (const float*)d_in[3];
    const float* k_w    = (const float*)d_in[4];
    const float* k_b    = (const float*)d_in[5];
    const float* rpb    = (const float*)d_in[6];
    const float* proj_w = (const float*)d_in[7];
    const float* proj_b = (const float*)d_in[8];
    const float* n1_w   = (const float*)d_in[9];
    const float* n1_b   = (const float*)d_in[10];
    const float* n2_w   = (const float*)d_in[11];
    const float* n2_b   = (const float*)d_in[12];
    const float* fc1_w  = (const float*)d_in[13];
    const float* fc1_b  = (const float*)d_in[14];
    const float* fc2_w  = (const float*)d_in[15];
    const float* fc2_b  = (const float*)d_in[16];
    float* out = (float*)d_out;

    bf16* qb  = (bf16*)d_ws;                        // later reused as ao (alias)
    bf16* vb  = qb + (size_t)N_PIX * C;
    bf16* kb  = vb + (size_t)N_PIX * C;
    short* wqv  = (short*)(kb + (size_t)N_PIX * C); // 32768
    short* wk   = wqv + 32768;                      // 16384
    short* wproj= wk + 16384;                       // 16384
    short* wfc1 = wproj + 16384;                    // 65536
    short* wfc2 = wfc1 + 65536;                     // 65536  (total ~12.4 MB)
    bf16* ao = qb;                                  // alias: safe (see k_attn)

    k_wconv<<<256, 256, 0, stream>>>(qv_w, k_w, proj_w, fc1_w, fc2_w,
                                     wqv, wk, wproj, wfc1, wfc2);
    k_qkv<<<N_PIX / 32, 512, 0, stream>>>(x, y, wqv, qv_b, wk, k_b, n1_w, n1_b, qb, vb, kb);
    k_attn<<<1024, 256, 0, stream>>>(qb, kb, vb, rpb, ao);
    k_mlp2<<<N_PIX / 32, 512, 0, stream>>>(x, ao, wproj, proj_b, n2_w, n2_b,
                                           wfc1, fc1_b, wfc2, fc2_b, out);
}

// Round 11
// 173.134 us; speedup vs baseline: 1.4445x; 1.0031x over previous
//
#include <hip/hip_runtime.h>
#include <hip/hip_bf16.h>

// CrossNATBlock2D: B=1, H=W=128, C=128, HEADS=4, HD=32, K=7  (fp32 I/O)
// R11: k_attn + k_mlp2 fused per 4x4 tile (zero redundant work; M=16 is native
// MFMA M). LDS phase-aliased into K/V buffers: 52.9 KB -> 3 blocks/CU.
// k_qkv/k_wconv unchanged from R10. No ao global round-trip.

#define N_PIX 16384
#define C 128
#define HEADS 4
#define HD 32
#define HW 128

typedef __hip_bfloat16 bf16;
typedef __attribute__((ext_vector_type(8))) short bf16x8;
typedef __attribute__((ext_vector_type(4))) float f32x4;

__device__ __forceinline__ short f2bs(float f) {
    bf16 h = __float2bfloat16(f);
    return (short)__bfloat16_as_ushort(h);
}
__device__ __forceinline__ float bs2f(short s) {
    __hip_bfloat16_raw r; r.x = (unsigned short)s;
    return __bfloat162float(__hip_bfloat16(r));
}
__device__ __forceinline__ float gelu_f(float v) {
    const float z = 1.5957691216f * (v + 0.044715f * v * v * v);
    return v / (1.f + __expf(-z));  // == 0.5v(1+tanh(z/2))
}

// ---------- kernel 0: convert weights fp32 -> bf16 into ws ----------
__global__ __launch_bounds__(256) void k_wconv(
    const float* __restrict__ qv_w, const float* __restrict__ k_w,
    const float* __restrict__ proj_w, const float* __restrict__ fc1_w,
    const float* __restrict__ fc2_w,
    short* __restrict__ wqv, short* __restrict__ wk, short* __restrict__ wproj,
    short* __restrict__ wfc1, short* __restrict__ wfc2) {
    const int i = blockIdx.x * 256 + threadIdx.x;
    if (i < 32768) wqv[i] = f2bs(qv_w[i]);
    if (i < 16384) { wk[i] = f2bs(k_w[i]); wproj[i] = f2bs(proj_w[i]); }
    if (i < 65536) { wfc1[i] = f2bs(fc1_w[i]); wfc2[i] = f2bs(fc2_w[i]); }
}

// ---------- kernel 1: LN1 + QV GEMM + K proj (R10, unchanged) ----------
__global__ __launch_bounds__(512, 6) void k_qkv(
    const float* __restrict__ x, const float* __restrict__ y,
    const short* __restrict__ wqv, const float* __restrict__ qv_b,
    const short* __restrict__ wk, const float* __restrict__ k_b,
    const float* __restrict__ n1_w, const float* __restrict__ n1_b,
    bf16* __restrict__ qb, bf16* __restrict__ vb, bf16* __restrict__ kb) {
    __shared__ float xr[32][132];
    __shared__ short xn[32][136];
    __shared__ short yb[32][136];
    __shared__ float muA[32], riA[32];
    const int t = threadIdx.x;
    const int pix0 = blockIdx.x * 32;
    for (int e = t; e < 32 * 128; e += 512) {
        const int r = e >> 7, c = e & 127;
        xr[r][c] = x[(pix0 + r) * C + c];
        yb[r][c] = f2bs(y[(pix0 + r) * C + c]);
    }
    __syncthreads();
    if (t < 256) {
        const int r = t >> 3, s = t & 7;
        float sm = 0.f, sq = 0.f;
        for (int i = 0; i < 16; i++) { float v = xr[r][s * 16 + i]; sm += v; sq += v * v; }
        for (int m = 1; m < 8; m <<= 1) { sm += __shfl_xor(sm, m, 64); sq += __shfl_xor(sq, m, 64); }
        if (s == 0) {
            const float mu = sm * (1.f / 128.f);
            const float var = sq * (1.f / 128.f) - mu * mu;
            muA[r] = mu; riA[r] = rsqrtf(var + 1e-5f);
        }
    }
    __syncthreads();
    for (int e = t; e < 32 * 128; e += 512) {
        const int r = e >> 7, c = e & 127;
        xn[r][c] = f2bs((xr[r][c] - muA[r]) * riA[r] * n1_w[c] + n1_b[c]);
    }
    __syncthreads();
    const int wave = t >> 6, lane = t & 63, quad = lane >> 4, l15 = lane & 15;
    const float scale = 0.1767766952966369f;  // 1/sqrt(32)
    for (int jt = wave; jt < 48; jt += 8) {
        const int mt = jt & 1, nt = jt >> 1;
        f32x4 acc = {0.f, 0.f, 0.f, 0.f};
        if (nt < 16) {
            const int n = nt * 16 + l15;
            for (int kt = 0; kt < 4; kt++) {
                bf16x8 a = *(const bf16x8*)&xn[mt * 16 + l15][kt * 32 + quad * 8];
                bf16x8 b = *(const bf16x8*)&wqv[n * C + kt * 32 + quad * 8];
                acc = __builtin_amdgcn_mfma_f32_16x16x32_bf16(a, b, acc, 0, 0, 0);
            }
            const float bias = qv_b[n];
            for (int r = 0; r < 4; r++) {
                const int m = mt * 16 + quad * 4 + r;
                const float v = acc[r] + bias;
                if (n < C) qb[(pix0 + m) * C + n] = __float2bfloat16(v * scale);
                else       vb[(pix0 + m) * C + (n - C)] = __float2bfloat16(v);
            }
        } else {
            const int n = (nt - 16) * 16 + l15;
            for (int kt = 0; kt < 4; kt++) {
                bf16x8 a = *(const bf16x8*)&yb[mt * 16 + l15][kt * 32 + quad * 8];
                bf16x8 b = *(const bf16x8*)&wk[n * C + kt * 32 + quad * 8];
                acc = __builtin_amdgcn_mfma_f32_16x16x32_bf16(a, b, acc, 0, 0, 0);
            }
            const float bias = k_b[n];
            for (int r = 0; r < 4; r++) {
                const int m = mt * 16 + quad * 4 + r;
                kb[(pix0 + m) * C + n] = __float2bfloat16(acc[r] + bias);
            }
        }
    }
}

// ---------- kernel 2: fused attention + proj + residual + LN2 + MLP ----------
// one block per 4x4 tile (16 pixels). LDS phase map (shorts):
//   KP[13200]: K(100x132) -> P(64x136 @0) + aoL(16x136 @8704) + x1b(16x136 @10880)
//   Vl[13200]: V(100x132) -> hb(16x520 @0) + xn(16x136 @8320)
__global__ __launch_bounds__(256) void k_fam(
    const bf16* __restrict__ qb, const bf16* __restrict__ kb,
    const bf16* __restrict__ vb, const float* __restrict__ rpb,
    const float* __restrict__ x,
    const short* __restrict__ wproj, const float* __restrict__ proj_b,
    const float* __restrict__ n2_w, const float* __restrict__ n2_b,
    const short* __restrict__ wfc1, const float* __restrict__ fc1_b,
    const short* __restrict__ wfc2, const float* __restrict__ fc2_b,
    float* __restrict__ out) {
    __shared__ short KP[13200];
    __shared__ short Vl[13200];
    __shared__ float muA[16], riA[16];
    short* const Pm  = KP;            // 64 x 136
    short* const aoL = KP + 8704;     // 16 x 136
    short* const x1b = KP + 10880;    // 16 x 136
    short* const hb  = Vl;            // 16 x 520
    short* const xnb = Vl + 8320;     // 16 x 136
    const int t = threadIdx.x;
    const int h = t >> 6, lane = t & 63, quad = lane >> 4, l15 = lane & 15;
    const int i0 = (blockIdx.x >> 5) * 4;
    const int j0 = (blockIdx.x & 31) * 4;
    const int rs = min(max(i0 - 3, 0), 118);
    const int cs = min(max(j0 - 3, 0), 118);
    // ---- phase 1: stage K,V unions (100 rows x 128 ch) ----
    for (int u = t; u < 100 * 16 * 2; u += 256) {
        const int tv = (u >= 1600) ? 1 : 0;
        const int uu = tv ? u - 1600 : u;
        const int r = uu >> 4, seg = uu & 15;
        const size_t g = (size_t)((rs + r / 10) * HW + cs + r % 10) * C + seg * 8;
        const uint4 d = *(const uint4*)((tv ? vb : kb) + g);
        *(uint4*)&(tv ? Vl : KP)[r * 132 + seg * 8] = d;
    }
    __syncthreads();
    // ---- phase 2: QK^T + bias/mask + softmax (wave = head) ----
    const int pA = (i0 + (l15 >> 2)) * HW + j0 + (l15 & 3);
    const bf16x8 aQ = *(const bf16x8*)(qb + (size_t)pA * C + h * HD + quad * 8);
    f32x4 S[7];
    int aiL[7], ajL[7]; bool inb[7];
    for (int nt = 0; nt < 7; nt++) {
        const int nb = nt * 16 + l15;
        aiL[nt] = rs + nb / 10;
        ajL[nt] = cs + nb % 10;
        inb[nt] = nb < 100;
        const bf16x8 bK = *(const bf16x8*)&KP[(nt * 16 + l15) * 132 + h * HD + quad * 8];
        f32x4 z = {0.f, 0.f, 0.f, 0.f};
        S[nt] = __builtin_amdgcn_mfma_f32_16x16x32_bf16(aQ, bK, z, 0, 0, 0);
    }
    const float* rpbh = rpb + h * 169;
    float smx[4];
    for (int r = 0; r < 4; r++) {
        const int m = quad * 4 + r;
        const int i = i0 + (m >> 2), j = j0 + (m & 3);
        const int shi = min(max(i - 3, 0), 121);
        const int swj = min(max(j - 3, 0), 121);
        float best = -1e30f;
        for (int nt = 0; nt < 7; nt++) {
            const int ai = aiL[nt], aj = ajL[nt];
            const bool valid = inb[nt] & (ai >= shi) & (ai <= shi + 6) & (aj >= swj) & (aj <= swj + 6);
            const int ri = min(max(ai - i + 6, 0), 12);
            const int rj = min(max(aj - j + 6, 0), 12);
            const float v = valid ? (S[nt][r] + rpbh[ri * 13 + rj]) : -1e30f;
            S[nt][r] = v;
            best = fmaxf(best, v);
        }
        for (int msk = 1; msk < 16; msk <<= 1) best = fmaxf(best, __shfl_xor(best, msk, 64));
        float s = 0.f;
        for (int nt = 0; nt < 7; nt++) {
            const float e = __expf(S[nt][r] - best);
            S[nt][r] = e;
            s += e;
        }
        for (int msk = 1; msk < 16; msk <<= 1) s += __shfl_xor(s, msk, 64);
        smx[r] = 1.f / s;
    }
    __syncthreads();   // all K reads done
    // ---- phase 3: P (bf16) -> Pm rows h*16.., zero cols 112..127 ----
    for (int r = 0; r < 4; r++) {
        short* prow = &Pm[(h * 16 + quad * 4 + r) * 136];
        for (int nt = 0; nt < 7; nt++)
            prow[nt * 16 + l15] = f2bs(S[nt][r] * smx[r]);
        prow[112 + l15] = 0;
    }
    __syncthreads();
    // ---- phase 4: PV -> aoL (disjoint LDS region, no extra barrier) ----
    f32x4 O0 = {0.f, 0.f, 0.f, 0.f}, O1 = {0.f, 0.f, 0.f, 0.f};
    for (int kt = 0; kt < 4; kt++) {
        const bf16x8 aP = *(const bf16x8*)&Pm[(h * 16 + l15) * 136 + kt * 32 + quad * 8];
        for (int nt2 = 0; nt2 < 2; nt2++) {
            bf16x8 bV;
            const int ch = h * HD + nt2 * 16 + l15;
#pragma unroll
            for (int jj = 0; jj < 8; jj++) {
                const int nbr = kt * 32 + quad * 8 + jj;
                bV[jj] = (nbr < 100) ? Vl[nbr * 132 + ch] : (short)0;
            }
            if (nt2 == 0) O0 = __builtin_amdgcn_mfma_f32_16x16x32_bf16(aP, bV, O0, 0, 0, 0);
            else          O1 = __builtin_amdgcn_mfma_f32_16x16x32_bf16(aP, bV, O1, 0, 0, 0);
        }
    }
    for (int r = 0; r < 4; r++) {
        const int m = quad * 4 + r;
        aoL[m * 136 + h * HD + l15] = f2bs(O0[r]);
        aoL[m * 136 + h * HD + 16 + l15] = f2bs(O1[r]);
    }
    __syncthreads();
    // ---- phase 5: proj + residual -> x1b (M=16) ----
    for (int jt = h; jt < 8; jt += 4) {
        const int n = jt * 16 + l15;
        f32x4 acc = {0.f, 0.f, 0.f, 0.f};
        for (int kt = 0; kt < 4; kt++) {
            bf16x8 a = *(const bf16x8*)&aoL[l15 * 136 + kt * 32 + quad * 8];
            bf16x8 b = *(const bf16x8*)&wproj[n * C + kt * 32 + quad * 8];
            acc = __builtin_amdgcn_mfma_f32_16x16x32_bf16(a, b, acc, 0, 0, 0);
        }
        const float bias = proj_b[n];
        for (int r = 0; r < 4; r++) {
            const int m = quad * 4 + r;
            const int p = (i0 + (m >> 2)) * HW + j0 + (m & 3);
            x1b[m * 136 + n] = f2bs(x[(size_t)p * C + n] + acc[r] + bias);
        }
    }
    __syncthreads();
    // ---- phase 6: LN2 stats (16 rows, 8 lanes/row over waves 0-1) ----
    if (t < 128) {
        const int r = t >> 3, s = t & 7;
        float sm = 0.f, sq = 0.f;
        for (int i = 0; i < 16; i++) { float v = bs2f(x1b[r * 136 + s * 16 + i]); sm += v; sq += v * v; }
        for (int m = 1; m < 8; m <<= 1) { sm += __shfl_xor(sm, m, 64); sq += __shfl_xor(sq, m, 64); }
        if (s == 0) {
            const float mu = sm * (1.f / 128.f);
            const float var = sq * (1.f / 128.f) - mu * mu;
            muA[r] = mu; riA[r] = rsqrtf(var + 1e-5f);
        }
    }
    __syncthreads();
    // ---- phase 7: xn = LN(x1) -> xnb (V region dead) ----
    for (int e = t; e < 16 * 128; e += 256) {
        const int r = e >> 7, c = e & 127;
        xnb[r * 136 + c] = f2bs((bs2f(x1b[r * 136 + c]) - muA[r]) * riA[r] * n2_w[c] + n2_b[c]);
    }
    __syncthreads();
    // ---- phase 8: fc1 + gelu -> hb ----
    for (int jt = h; jt < 32; jt += 4) {
        const int n = jt * 16 + l15;
        f32x4 acc = {0.f, 0.f, 0.f, 0.f};
        for (int kt = 0; kt < 4; kt++) {
            bf16x8 a = *(const bf16x8*)&xnb[l15 * 136 + kt * 32 + quad * 8];
            bf16x8 b = *(const bf16x8*)&wfc1[n * C + kt * 32 + quad * 8];
            acc = __builtin_amdgcn_mfma_f32_16x16x32_bf16(a, b, acc, 0, 0, 0);
        }
        const float bias = fc1_b[n];
        for (int r = 0; r < 4; r++)
            hb[(quad * 4 + r) * 520 + n] = f2bs(gelu_f(acc[r] + bias));
    }
    __syncthreads();
    // ---- phase 9: fc2 + residual -> out ----
    for (int jt = h; jt < 8; jt += 4) {
        const int n = jt * 16 + l15;
        f32x4 acc = {0.f, 0.f, 0.f, 0.f};
#pragma unroll
        for (int kt = 0; kt < 16; kt++) {
            bf16x8 a = *(const bf16x8*)&hb[l15 * 520 + kt * 32 + quad * 8];
            bf16x8 b = *(const bf16x8*)&wfc2[n * 512 + kt * 32 + quad * 8];
            acc = __builtin_amdgcn_mfma_f32_16x16x32_bf16(a, b, acc, 0, 0, 0);
        }
        const float bias = fc2_b[n];
        for (int r = 0; r < 4; r++) {
            const int m = quad * 4 + r;
            const int p = (i0 + (m >> 2)) * HW + j0 + (m & 3);
            out[(size_t)p * C + n] = acc[r] + bias + bs2f(x1b[m * 136 + n]);
        }
    }
}

extern "C" void kernel_launch(void* const* d_in, const int* in_sizes, int n_in,
                              void* d_out, int out_size, void* d_ws, size_t ws_size,
                              hipStream_t stream) {
    const float* x      = (const float*)d_in[0];
    const float* y      = (const float*)d_in[1];
    const float* qv_w   = (const float*)d_in[2];
    const float* qv_b   = (const float*)d_in[3];
    const float* k_w    = (const float*)d_in[4];
    const float* k_b    = (const float*)d_in[5];
    const float* rpb    = (const float*)d_in[6];
    const float* proj_w = (const float*)d_in[7];
    const float* proj_b = (const float*)d_in[8];
    const float* n1_w   = (const float*)d_in[9];
    const float* n1_b   = (const float*)d_in[10];
    const float* n2_w   = (const float*)d_in[11];
    const float* n2_b   = (const float*)d_in[12];
    const float* fc1_w  = (const float*)d_in[13];
    const float* fc1_b  = (const float*)d_in[14];
    const float* fc2_w  = (const float*)d_in[15];
    const float* fc2_b  = (const float*)d_in[16];
    float* out = (float*)d_out;

    bf16* qb  = (bf16*)d_ws;
    bf16* vb  = qb + (size_t)N_PIX * C;
    bf16* kb  = vb + (size_t)N_PIX * C;
    short* wqv  = (short*)(kb + (size_t)N_PIX * C); // 32768
    short* wk   = wqv + 32768;                      // 16384
    short* wproj= wk + 16384;                       // 16384
    short* wfc1 = wproj + 16384;                    // 65536
    short* wfc2 = wfc1 + 65536;                     // 65536  (total ~12.4 MB)

    k_wconv<<<256, 256, 0, stream>>>(qv_w, k_w, proj_w, fc1_w, fc2_w,
                                     wqv, wk, wproj, wfc1, wfc2);
    k_qkv<<<N_PIX / 32, 512, 0, stream>>>(x, y, wqv, qv_b, wk, k_b, n1_w, n1_b, qb, vb, kb);
    k_fam<<<1024, 256, 0, stream>>>(qb, kb, vb, rpb, x, wproj, proj_b, n2_w, n2_b,
                                    wfc1, fc1_b, wfc2, fc2_b, out);
}